// Round 10
// baseline (38.983 us; speedup 1.0000x reference)
//
#include <hip/hip_runtime.h>
#include <math.h>
#include <utility>

static constexpr int HH = 2048;
static constexpr int WW = 2048;
static constexpr int NPIX = HH * WW;
static constexpr int WPR32 = WW / 32;      // 64 packed u32 words per row

// Compile-time-forced loop unrolling (keeps acc[] in registers).
template <typename F, int... Is>
__device__ __forceinline__ void sf_impl(F&& f, std::integer_sequence<int, Is...>) {
    (f(std::integral_constant<int, Is>{}), ...);
}
template <int N, typename F>
__device__ __forceinline__ void static_for(F&& f) {
    sf_impl(f, std::make_integer_sequence<int, N>{});
}

// Rank of squared distance among the 14 distinct d2 values in the 9x9
// neighborhood (ascending). 0 = "no differing neighbor".
__host__ __device__ constexpr int rank_of(int d2) {
    switch (d2) {
        case 1:  return 1;  case 2:  return 2;  case 4:  return 3;
        case 5:  return 4;  case 8:  return 5;  case 9:  return 6;
        case 10: return 7;  case 13: return 8;  case 16: return 9;
        case 17: return 10; case 18: return 11; case 20: return 12;
        case 25: return 13; case 32: return 14;
    }
    return 0;
}

__device__ const int D2S[16] = {0, 1, 2, 4, 5, 8, 9, 10, 13, 16, 17, 18, 20, 25, 32, 0};

// Spread the 8 bits of b into the 8 bytes of a u64 (byte i = (b>>i)&1).
__device__ __forceinline__ unsigned long long spread8(unsigned int b) {
    unsigned long long t = (unsigned long long)b * 0x0101010101010101ull;
    t &= 0x8040201008040201ull;
    return ((t + 0x7f7f7f7f7f7f7f7full) >> 7) & 0x0101010101010101ull;
}

// Pass A: fw byte map (sum of 5 binary masks) + bit-packed combined mask.
__global__ __launch_bounds__(256) void k_pack(const float* __restrict__ t,
                                              unsigned char* __restrict__ fw,
                                              unsigned char* __restrict__ pk) {
    const int tid = blockIdx.x * 256 + threadIdx.x;
    const int base = tid * 8;
    unsigned long long fwq = 0;
    unsigned int bits = 0;
#pragma unroll
    for (int h = 0; h < 2; ++h) {
        const int o = base + 4 * h;
        float4 a = *(const float4*)(t + 0 * NPIX + o);
        float4 b = *(const float4*)(t + 1 * NPIX + o);
        float4 c = *(const float4*)(t + 2 * NPIX + o);
        float4 d = *(const float4*)(t + 3 * NPIX + o);
        float4 e = *(const float4*)(t + 4 * NPIX + o);
        const float s0 = a.x + b.x + c.x + d.x + e.x;
        const float s1 = a.y + b.y + c.y + d.y + e.y;
        const float s2 = a.z + b.z + c.z + d.z + e.z;
        const float s3 = a.w + b.w + c.w + d.w + e.w;
        const int j = 4 * h;
        fwq |= ((unsigned long long)(int)s0) << (8 * j);
        fwq |= ((unsigned long long)(int)s1) << (8 * (j + 1));
        fwq |= ((unsigned long long)(int)s2) << (8 * (j + 2));
        fwq |= ((unsigned long long)(int)s3) << (8 * (j + 3));
        bits |= (s0 > 0.f ? 1u : 0u) << j;
        bits |= (s1 > 0.f ? 1u : 0u) << (j + 1);
        bits |= (s2 > 0.f ? 1u : 0u) << (j + 2);
        bits |= (s3 > 0.f ? 1u : 0u) << (j + 3);
    }
    *(unsigned long long*)(fw + base) = fwq;
    pk[tid] = (unsigned char)bits;
}

// Pass B: bit-parallel min-squared-distance classification.
// R10 change vs R9 (single variable): fw8 prefetched as 2x 16-B vector loads
// ISSUED BEFORE the LDS barrier (latency hides under tile load + neighborhood
// compute), and code8 emitted as 2x 16-B vector stores. No atomics (R9 win).
__global__ __launch_bounds__(512) void k_dist(const unsigned* __restrict__ pk32,
                                              const unsigned long long* __restrict__ fw8,
                                              unsigned long long* __restrict__ code8,
                                              unsigned long long* __restrict__ obs_slots) {
    __shared__ unsigned tile[16][WPR32];   // 16 rows x 64 u32 = 4 KB

    const int y0 = blockIdx.x * 8;
    const int ty = threadIdx.x >> 6;           // 0..7 (row within block)
    const int wx = threadIdx.x & 63;           // u32 word within row
    const int t = (y0 + ty) * WPR32 + wx;      // global u32-word index

    // Prefetch this thread's 32 fv bytes (4 u64) early — consumed only in the
    // epilogue, so ~900cy of load latency hides under the whole compute phase.
    const ulonglong2 f01 = *(const ulonglong2*)(fw8 + t * 4);
    const ulonglong2 f23 = *(const ulonglong2*)(fw8 + t * 4 + 2);

    // Cooperative halo load: rows clamp(y0-4 .. y0+11), full width.
#pragma unroll
    for (int k = 0; k < 2; ++k) {
        const int idx = threadIdx.x + k * 512;
        const int r = idx >> 6;
        const int hwx = idx & 63;
        const int gy = min(max(y0 - 4 + r, 0), HH - 1);
        tile[r][hwx] = pk32[gy * WPR32 + hwx];
    }
    __syncthreads();

    unsigned acc[15];
    static_for<15>([&](auto I) { acc[I.value] = 0u; });

    const unsigned C = tile[ty + 4][wx];

    static_for<9>([&](auto DY) {
        constexpr int dy = DY.value - 4;
        const int r = ty + dy + 4;
        const unsigned M = tile[r][wx];
        const unsigned L = (wx > 0) ? tile[r][wx - 1] : ((M & 1u) ? ~0u : 0u);
        const unsigned R = (wx < WPR32 - 1) ? tile[r][wx + 1]
                                            : ((M >> 31) ? ~0u : 0u);
        static_for<9>([&](auto DX) {
            constexpr int dx = DX.value - 4;
            if constexpr (!(dx == 0 && dy == 0)) {
                constexpr int rk = rank_of(dy * dy + dx * dx);
                unsigned S;
                if constexpr (dx > 0)      S = (M >> dx) | (R << (32 - dx));
                else if constexpr (dx < 0) S = (M << (-dx)) | (L >> (32 + dx));
                else                       S = M;
                acc[rk] |= S ^ C;
            }
        });
    });

    // Resolve ascending distance into 4 bitplanes (first-found = min d2).
    unsigned found = 0, p0 = 0, p1 = 0, p2 = 0, p3 = 0;
    static_for<14>([&](auto RI) {
        constexpr int r = RI.value + 1;
        const unsigned nw = acc[r] & ~found;
        found |= acc[r];
        if constexpr (r & 1) p0 |= nw;
        if constexpr (r & 2) p1 |= nw;
        if constexpr (r & 4) p2 |= nw;
        if constexpr (r & 8) p3 |= nw;
    });

    // Epilogue: assemble code bytes (code = fv<<4 | class); track observed.
    unsigned long long cq[4];
    unsigned long long lo = 0, hi = 0;
    static_for<4>([&](auto J) {
        constexpr int j = J.value;
        const unsigned long long f = (j == 0) ? f01.x : (j == 1) ? f01.y
                                   : (j == 2) ? f23.x : f23.y;
        const unsigned int c0 = (p0 >> (8 * j)) & 0xff;
        const unsigned int c1 = (p1 >> (8 * j)) & 0xff;
        const unsigned int c2 = (p2 >> (8 * j)) & 0xff;
        const unsigned int c3 = (p3 >> (8 * j)) & 0xff;
        const unsigned long long cls = spread8(c0) | (spread8(c1) << 1)
                                     | (spread8(c2) << 2) | (spread8(c3) << 3);
        cq[j] = (f << 4) | cls;   // fv<=5, no nibble overflow
        static_for<8>([&](auto B) {
            constexpr int b = B.value;
            const unsigned int code = (unsigned int)((cq[j] >> (8 * b)) & 0xff);
            const unsigned long long bit = 1ull << (code & 63);
            const bool ishi = (code & 64) != 0;
            lo |= ishi ? 0ull : bit;
            hi |= ishi ? bit : 0ull;
        });
    });
    *(ulonglong2*)(code8 + t * 4)     = make_ulonglong2(cq[0], cq[1]);
    *(ulonglong2*)(code8 + t * 4 + 2) = make_ulonglong2(cq[2], cq[3]);

    // Wave OR-reduce, then ONE plain store pair per wave (disjoint slots).
#pragma unroll
    for (int s = 32; s > 0; s >>= 1) {
        lo |= __shfl_xor(lo, s);
        hi |= __shfl_xor(hi, s);
    }
    if ((threadIdx.x & 63) == 0) {
        const int wave = blockIdx.x * 8 + (threadIdx.x >> 6);
        obs_slots[wave * 2]     = lo;
        obs_slots[wave * 2 + 1] = hi;
    }
}

// Pass C: OR-reduce the 2048 per-wave obs slots (32 KB, L2-broadcast), build
// the 96-entry table, then LDS-table lookup.
__global__ __launch_bounds__(256) void k_out(const unsigned long long* __restrict__ code8,
                                             const unsigned long long* __restrict__ obs_slots,
                                             float* __restrict__ out) {
    __shared__ float tab[96];
    __shared__ float smn[4], smx[4];
    __shared__ unsigned long long slo[4], shi[4];

    const int tid = threadIdx.x;

    // Preamble: global obs = OR of all per-wave slots.
    unsigned long long lo = 0, hi = 0;
    {
        const ulonglong2* sl2 = (const ulonglong2*)obs_slots;
#pragma unroll
        for (int i = 0; i < 8; ++i) {
            const ulonglong2 s = sl2[tid * 8 + i];   // 256 thr x 8 = 2048 slots
            lo |= s.x;
            hi |= s.y;
        }
#pragma unroll
        for (int s = 32; s > 0; s >>= 1) {
            lo |= __shfl_xor(lo, s);
            hi |= __shfl_xor(hi, s);
        }
        if ((tid & 63) == 0) { slo[tid >> 6] = lo; shi[tid >> 6] = hi; }
        __syncthreads();
        lo = slo[0] | slo[1] | slo[2] | slo[3];
        hi = shi[0] | shi[1] | shi[2] | shi[3];
    }

    float v = 0.f;
    bool present = false;
    if (tid < 96) {
        const int r = tid & 15;
        const float contour = (r >= 1 && r <= 14) ? 1.f / sqrtf((float)D2S[r]) : 0.f;
        const float t0 = (float)(tid >> 4) + contour;
        v = t0 * t0;
        present = (tid < 64) ? ((lo >> tid) & 1) : ((hi >> (tid - 64)) & 1);
    }
    float mnv = present ? v : INFINITY;
    float mxv = present ? v : -INFINITY;
#pragma unroll
    for (int s = 32; s > 0; s >>= 1) {
        mnv = fminf(mnv, __shfl_xor(mnv, s));
        mxv = fmaxf(mxv, __shfl_xor(mxv, s));
    }
    if ((tid & 63) == 0) { smn[tid >> 6] = mnv; smx[tid >> 6] = mxv; }
    __syncthreads();
    const float mn = fminf(fminf(smn[0], smn[1]), fminf(smn[2], smn[3]));
    const float mx = fmaxf(fmaxf(smx[0], smx[1]), fmaxf(smx[2], smx[3]));
    const float inv = 1.f / (mx - mn + 1e-10f);
    if (tid < 96) tab[tid] = (tid >= 16) ? (v - mn) * inv : 0.f;  // fv==0 -> 0
    __syncthreads();

    const int t = blockIdx.x * 256 + tid;
    const unsigned long long cq = code8[t];
    float4 v0, v1;
    v0.x = tab[(cq >> 0) & 0xff];
    v0.y = tab[(cq >> 8) & 0xff];
    v0.z = tab[(cq >> 16) & 0xff];
    v0.w = tab[(cq >> 24) & 0xff];
    v1.x = tab[(cq >> 32) & 0xff];
    v1.y = tab[(cq >> 40) & 0xff];
    v1.z = tab[(cq >> 48) & 0xff];
    v1.w = tab[(cq >> 56) & 0xff];
    *(float4*)(out + t * 8) = v0;
    *(float4*)(out + t * 8 + 4) = v1;
}

extern "C" void kernel_launch(void* const* d_in, const int* in_sizes, int n_in,
                              void* d_out, int out_size, void* d_ws, size_t ws_size,
                              hipStream_t stream) {
    const float* target = (const float*)d_in[0];
    float* out = (float*)d_out;

    // ws layout (16B-aligned sections): fw | packed | code | obs_slots
    unsigned char* fw = (unsigned char*)d_ws;                         // NPIX bytes
    unsigned char* pk = fw + NPIX;                                    // NPIX/8 bytes
    unsigned char* code = pk + NPIX / 8;                              // NPIX bytes
    unsigned long long* obs_slots = (unsigned long long*)(code + NPIX); // 2048*16 B

    k_pack<<<NPIX / 8 / 256, 256, 0, stream>>>(target, fw, pk);

    k_dist<<<HH / 8, 512, 0, stream>>>(
        (const unsigned*)pk, (const unsigned long long*)fw,
        (unsigned long long*)code, obs_slots);

    k_out<<<NPIX / 8 / 256, 256, 0, stream>>>(
        (const unsigned long long*)code, obs_slots, out);
}

// Round 11
// 36.812 us; speedup vs baseline: 1.0590x; 1.0590x over previous
//
#include <hip/hip_runtime.h>
#include <math.h>
#include <utility>

static constexpr int HH = 2048;
static constexpr int WW = 2048;
static constexpr int NPIX = HH * WW;
static constexpr int WPR32 = WW / 32;      // 64 packed u32 words per row
static constexpr int HPR = WW / 16;        // 128 u16 chunks per row

// Compile-time-forced loop unrolling (keeps acc[] in registers).
template <typename F, int... Is>
__device__ __forceinline__ void sf_impl(F&& f, std::integer_sequence<int, Is...>) {
    (f(std::integral_constant<int, Is>{}), ...);
}
template <int N, typename F>
__device__ __forceinline__ void static_for(F&& f) {
    sf_impl(f, std::make_integer_sequence<int, N>{});
}

// Rank of squared distance among the 14 distinct d2 values in the 9x9
// neighborhood (ascending). 0 = "no differing neighbor".
__host__ __device__ constexpr int rank_of(int d2) {
    switch (d2) {
        case 1:  return 1;  case 2:  return 2;  case 4:  return 3;
        case 5:  return 4;  case 8:  return 5;  case 9:  return 6;
        case 10: return 7;  case 13: return 8;  case 16: return 9;
        case 17: return 10; case 18: return 11; case 20: return 12;
        case 25: return 13; case 32: return 14;
    }
    return 0;
}

__device__ const int D2S[16] = {0, 1, 2, 4, 5, 8, 9, 10, 13, 16, 17, 18, 20, 25, 32, 0};

// Spread the 8 bits of b into the 8 bytes of a u64 (byte i = (b>>i)&1).
__device__ __forceinline__ unsigned long long spread8(unsigned int b) {
    unsigned long long t = (unsigned long long)b * 0x0101010101010101ull;
    t &= 0x8040201008040201ull;
    return ((t + 0x7f7f7f7f7f7f7f7full) >> 7) & 0x0101010101010101ull;
}

// Pass A: fw byte map (sum of 5 binary masks) + bit-packed combined mask.
__global__ __launch_bounds__(256) void k_pack(const float* __restrict__ t,
                                              unsigned char* __restrict__ fw,
                                              unsigned char* __restrict__ pk) {
    const int tid = blockIdx.x * 256 + threadIdx.x;
    const int base = tid * 8;
    unsigned long long fwq = 0;
    unsigned int bits = 0;
#pragma unroll
    for (int h = 0; h < 2; ++h) {
        const int o = base + 4 * h;
        float4 a = *(const float4*)(t + 0 * NPIX + o);
        float4 b = *(const float4*)(t + 1 * NPIX + o);
        float4 c = *(const float4*)(t + 2 * NPIX + o);
        float4 d = *(const float4*)(t + 3 * NPIX + o);
        float4 e = *(const float4*)(t + 4 * NPIX + o);
        const float s0 = a.x + b.x + c.x + d.x + e.x;
        const float s1 = a.y + b.y + c.y + d.y + e.y;
        const float s2 = a.z + b.z + c.z + d.z + e.z;
        const float s3 = a.w + b.w + c.w + d.w + e.w;
        const int j = 4 * h;
        fwq |= ((unsigned long long)(int)s0) << (8 * j);
        fwq |= ((unsigned long long)(int)s1) << (8 * (j + 1));
        fwq |= ((unsigned long long)(int)s2) << (8 * (j + 2));
        fwq |= ((unsigned long long)(int)s3) << (8 * (j + 3));
        bits |= (s0 > 0.f ? 1u : 0u) << j;
        bits |= (s1 > 0.f ? 1u : 0u) << (j + 1);
        bits |= (s2 > 0.f ? 1u : 0u) << (j + 2);
        bits |= (s3 > 0.f ? 1u : 0u) << (j + 3);
    }
    *(unsigned long long*)(fw + base) = fwq;
    pk[tid] = (unsigned char)bits;
}

// Pass B: bit-parallel min-squared-distance classification at u16 grain.
// R11 vs R10: one thread per 16-px chunk (262144 threads = 4 waves/SIMD,
// 2x the occupancy) via a 24-bit window W per row: every dx is ONE u64
// shift + xor + or. Per-block obs slot (LDS-combined) instead of per-wave.
__global__ __launch_bounds__(1024) void k_dist(const unsigned* __restrict__ pk32,
                                               const ulonglong2* __restrict__ fw16,
                                               ulonglong2* __restrict__ code16,
                                               unsigned long long* __restrict__ obs_blk) {
    __shared__ unsigned tile[16][WPR32];   // 16 rows x 64 u32 = 4 KB
    __shared__ unsigned long long swl[16], swh[16];

    const int y0 = blockIdx.x * 8;
    // Tile halo load: exactly one u32 per thread (16 rows x 64 words).
    {
        const int r = threadIdx.x >> 6;
        const int c = threadIdx.x & 63;
        const int gy = min(max(y0 - 4 + r, 0), HH - 1);
        tile[r][c] = pk32[gy * WPR32 + c];
    }

    const int ty = threadIdx.x >> 7;        // 0..7 row within block
    const int hx = threadIdx.x & 127;       // u16 chunk within row
    const int wx = hx >> 1;                 // owning u32 word
    const int h = hx & 1;                   // low/high half
    const int chunk = (y0 + ty) * HPR + hx; // global chunk index

    // Prefetch this chunk's 16 fv bytes (consumed only in the epilogue).
    const ulonglong2 fv2 = fw16[chunk];

    __syncthreads();

    unsigned acc[15];
    static_for<15>([&](auto I) { acc[I.value] = 0u; });

    const unsigned Cw = tile[ty + 4][wx];
    const unsigned C = h ? (Cw >> 16) : (Cw & 0xffffu);

    static_for<9>([&](auto DY) {
        constexpr int dy = DY.value - 4;
        const int r = ty + dy + 4;
        const unsigned M = tile[r][wx];
        unsigned long long W;
        if (h == 0) {
            // bits [-4, 20) of this chunk: P[28..31] ++ M[0..19]
            const unsigned P = (wx > 0) ? tile[r][wx - 1] : ((M & 1u) ? ~0u : 0u);
            W = ((unsigned long long)M << 4) | (P >> 28);
        } else {
            // bits [-4, 20) rel. to bit16: M[12..31] ++ N[0..3]
            const unsigned N = (wx < WPR32 - 1) ? tile[r][wx + 1]
                                                : ((M >> 31) ? ~0u : 0u);
            W = ((unsigned long long)N << 20) | (M >> 12);
        }
        static_for<9>([&](auto DX) {
            constexpr int dx = DX.value - 4;
            if constexpr (!(dx == 0 && dy == 0)) {
                constexpr int rk = rank_of(dy * dy + dx * dx);
                const unsigned S = (unsigned)(W >> (4 + dx));
                acc[rk] |= S ^ C;   // bits >=16 are garbage; never read
            }
        });
    });

    // Resolve ascending distance into 4 bitplanes (first-found = min d2).
    unsigned found = 0, p0 = 0, p1 = 0, p2 = 0, p3 = 0;
    static_for<14>([&](auto RI) {
        constexpr int r = RI.value + 1;
        const unsigned nw = acc[r] & ~found;
        found |= acc[r];
        if constexpr (r & 1) p0 |= nw;
        if constexpr (r & 2) p1 |= nw;
        if constexpr (r & 4) p2 |= nw;
        if constexpr (r & 8) p3 |= nw;
    });

    // Epilogue: assemble 16 code bytes (code = fv<<4 | cls); track observed.
    unsigned long long cq0 = 0, cq1 = 0;
    unsigned long long lo = 0, hi = 0;
    static_for<2>([&](auto J) {
        constexpr int j = J.value;
        const unsigned long long f = j ? fv2.y : fv2.x;
        const unsigned c0 = (p0 >> (8 * j)) & 0xff;
        const unsigned c1 = (p1 >> (8 * j)) & 0xff;
        const unsigned c2 = (p2 >> (8 * j)) & 0xff;
        const unsigned c3 = (p3 >> (8 * j)) & 0xff;
        const unsigned long long cls = spread8(c0) | (spread8(c1) << 1)
                                     | (spread8(c2) << 2) | (spread8(c3) << 3);
        const unsigned long long cq = (f << 4) | cls;   // fv<=5, no overflow
        if constexpr (j == 0) cq0 = cq; else cq1 = cq;
        static_for<8>([&](auto B) {
            constexpr int b = B.value;
            const unsigned code = (unsigned)((cq >> (8 * b)) & 0xff);
            const unsigned long long bit = 1ull << (code & 63);
            const bool ishi = (code & 64) != 0;
            lo |= ishi ? 0ull : bit;
            hi |= ishi ? bit : 0ull;
        });
    });
    code16[chunk] = make_ulonglong2(cq0, cq1);

    // Wave OR-reduce -> LDS -> single block slot pair (no atomics anywhere).
#pragma unroll
    for (int s = 32; s > 0; s >>= 1) {
        lo |= __shfl_xor(lo, s);
        hi |= __shfl_xor(hi, s);
    }
    const int wid = threadIdx.x >> 6;
    if ((threadIdx.x & 63) == 0) { swl[wid] = lo; swh[wid] = hi; }
    __syncthreads();
    if (threadIdx.x < 64) {
        unsigned long long l2 = (threadIdx.x < 16) ? swl[threadIdx.x] : 0ull;
        unsigned long long h2 = (threadIdx.x < 16) ? swh[threadIdx.x] : 0ull;
#pragma unroll
        for (int s = 8; s > 0; s >>= 1) {
            l2 |= __shfl_xor(l2, s);
            h2 |= __shfl_xor(h2, s);
        }
        if (threadIdx.x == 0) {
            obs_blk[blockIdx.x * 2] = l2;
            obs_blk[blockIdx.x * 2 + 1] = h2;
        }
    }
}

// Pass C: OR-reduce 256 per-block obs slots (4 KB), build 96-entry table,
// then 16-px-per-thread LDS-table lookup.
__global__ __launch_bounds__(256) void k_out(const ulonglong2* __restrict__ code16,
                                             const unsigned long long* __restrict__ obs_blk,
                                             float* __restrict__ out) {
    __shared__ float tab[96];
    __shared__ float smn[4], smx[4];
    __shared__ unsigned long long slo[4], shi[4];

    const int tid = threadIdx.x;

    // Preamble: global obs = OR of all 256 block slots (one pair per thread).
    unsigned long long lo, hi;
    {
        const ulonglong2 s = ((const ulonglong2*)obs_blk)[tid];
        lo = s.x;
        hi = s.y;
#pragma unroll
        for (int s2 = 32; s2 > 0; s2 >>= 1) {
            lo |= __shfl_xor(lo, s2);
            hi |= __shfl_xor(hi, s2);
        }
        if ((tid & 63) == 0) { slo[tid >> 6] = lo; shi[tid >> 6] = hi; }
        __syncthreads();
        lo = slo[0] | slo[1] | slo[2] | slo[3];
        hi = shi[0] | shi[1] | shi[2] | shi[3];
    }

    float v = 0.f;
    bool present = false;
    if (tid < 96) {
        const int r = tid & 15;
        const float contour = (r >= 1 && r <= 14) ? 1.f / sqrtf((float)D2S[r]) : 0.f;
        const float t0 = (float)(tid >> 4) + contour;
        v = t0 * t0;
        present = (tid < 64) ? ((lo >> tid) & 1) : ((hi >> (tid - 64)) & 1);
    }
    float mnv = present ? v : INFINITY;
    float mxv = present ? v : -INFINITY;
#pragma unroll
    for (int s = 32; s > 0; s >>= 1) {
        mnv = fminf(mnv, __shfl_xor(mnv, s));
        mxv = fmaxf(mxv, __shfl_xor(mxv, s));
    }
    if ((tid & 63) == 0) { smn[tid >> 6] = mnv; smx[tid >> 6] = mxv; }
    __syncthreads();
    const float mn = fminf(fminf(smn[0], smn[1]), fminf(smn[2], smn[3]));
    const float mx = fmaxf(fmaxf(smx[0], smx[1]), fmaxf(smx[2], smx[3]));
    const float inv = 1.f / (mx - mn + 1e-10f);
    if (tid < 96) tab[tid] = (tid >= 16) ? (v - mn) * inv : 0.f;  // fv==0 -> 0
    __syncthreads();

    // 16 px per thread: one ulonglong2 of codes -> 4 float4 stores.
    const int t = blockIdx.x * 256 + tid;
    const ulonglong2 cq = code16[t];
    float4 v0, v1, v2, v3;
    v0.x = tab[(cq.x >> 0) & 0xff];  v0.y = tab[(cq.x >> 8) & 0xff];
    v0.z = tab[(cq.x >> 16) & 0xff]; v0.w = tab[(cq.x >> 24) & 0xff];
    v1.x = tab[(cq.x >> 32) & 0xff]; v1.y = tab[(cq.x >> 40) & 0xff];
    v1.z = tab[(cq.x >> 48) & 0xff]; v1.w = tab[(cq.x >> 56) & 0xff];
    v2.x = tab[(cq.y >> 0) & 0xff];  v2.y = tab[(cq.y >> 8) & 0xff];
    v2.z = tab[(cq.y >> 16) & 0xff]; v2.w = tab[(cq.y >> 24) & 0xff];
    v3.x = tab[(cq.y >> 32) & 0xff]; v3.y = tab[(cq.y >> 40) & 0xff];
    v3.z = tab[(cq.y >> 48) & 0xff]; v3.w = tab[(cq.y >> 56) & 0xff];
    const int ob = t * 16;
    *(float4*)(out + ob + 0)  = v0;
    *(float4*)(out + ob + 4)  = v1;
    *(float4*)(out + ob + 8)  = v2;
    *(float4*)(out + ob + 12) = v3;
}

extern "C" void kernel_launch(void* const* d_in, const int* in_sizes, int n_in,
                              void* d_out, int out_size, void* d_ws, size_t ws_size,
                              hipStream_t stream) {
    const float* target = (const float*)d_in[0];
    float* out = (float*)d_out;

    // ws layout (16B-aligned sections): fw | packed | code | obs_blk
    unsigned char* fw = (unsigned char*)d_ws;                         // NPIX bytes
    unsigned char* pk = fw + NPIX;                                    // NPIX/8 bytes
    unsigned char* code = pk + NPIX / 8;                              // NPIX bytes
    unsigned long long* obs_blk = (unsigned long long*)(code + NPIX); // 256*16 B

    k_pack<<<NPIX / 8 / 256, 256, 0, stream>>>(target, fw, pk);

    k_dist<<<HH / 8, 1024, 0, stream>>>(
        (const unsigned*)pk, (const ulonglong2*)fw,
        (ulonglong2*)code, obs_blk);

    k_out<<<NPIX / 16 / 256, 256, 0, stream>>>(
        (const ulonglong2*)code, obs_blk, out);
}